// Round 6
// baseline (1053.289 us; speedup 1.0000x reference)
//
#include <hip/hip_runtime.h>
#include <math.h>

#define BB 256
#define NN 184
#define HH 128
#define FF 8
#define TH 24
#define TF 24
#define KA 160       // augmented K (128 h + up to 10 x + pad)
#define NG 512       // 4 gate-parts x 128
#define RPAD 192     // padded row count (12 tiles of 16)
#define STRH 136     // Ah row stride (elems)
#define STRX 40      // Ax row stride (elems)
#define NT 1024      // threads per block (16 waves)

typedef __attribute__((ext_vector_type(8))) short bf16x8;
typedef __attribute__((ext_vector_type(4))) float f32x4;

__device__ __forceinline__ float sigmoidf_(float x) {
    return 1.0f / (1.0f + __expf(-x));
}
__device__ __forceinline__ float tanhf_(float x) {
    float s = (x >= 0.f) ? 1.f : -1.f;
    float e = __expf(-2.0f * fabsf(x));
    return s * (1.0f - e) / (1.0f + e);
}
__device__ __forceinline__ unsigned short f2bf(float f) {
    unsigned u = __float_as_uint(f);
    u += 0x7fffu + ((u >> 16) & 1u);
    return (unsigned short)(u >> 16);
}

// ---------------------------------------------------------------------------
// Build augmented bf16 weights Wa[512][160] (R, Z, NH, NX gate parts) and
// bias arrays barr[4][128]: R:bih+bhh, Z:bih+bhh, NH:bhh, NX:bih.
// ---------------------------------------------------------------------------
__global__ void prep_weights(const float* __restrict__ WhhH, const float* __restrict__ WihH,
                             const float* __restrict__ WhhF, const float* __restrict__ WihF,
                             const float* __restrict__ bihH, const float* __restrict__ bhhH,
                             const float* __restrict__ bihF, const float* __restrict__ bhhF,
                             unsigned short* __restrict__ WaH, unsigned short* __restrict__ WaF,
                             float* __restrict__ barrH, float* __restrict__ barrF) {
    int idx = blockIdx.x * 256 + threadIdx.x;
    if (idx < NG * KA) {
        int jp = idx / KA, k = idx % KA;
        int j = jp & 127, part = jp >> 7;
        float vh = 0.f, vf = 0.f;
        if (part <= 1) {              // R, Z: combined Whh | Wih
            int row = part * 128 + j;
            if (k < 128) { vh = WhhH[row * 128 + k]; vf = WhhF[row * 128 + k]; }
            else {
                if (k < 130) vh = WihH[row * 2 + (k - 128)];
                if (k < 138) vf = WihF[row * 10 + (k - 128)];
            }
        } else if (part == 2) {       // NH: h part of n-gate
            if (k < 128) { vh = WhhH[(256 + j) * 128 + k]; vf = WhhF[(256 + j) * 128 + k]; }
        } else {                      // NX: x part of n-gate
            if (k >= 128) {
                if (k < 130) vh = WihH[(256 + j) * 2 + (k - 128)];
                if (k < 138) vf = WihF[(256 + j) * 10 + (k - 128)];
            }
        }
        WaH[idx] = f2bf(vh); WaF[idx] = f2bf(vf);
    }
    if (idx < NG) {
        int j = idx & 127, part = idx >> 7;
        float bh, bf2;
        if (part == 0)      { bh = bihH[j] + bhhH[j];             bf2 = bihF[j] + bhhF[j]; }
        else if (part == 1) { bh = bihH[128 + j] + bhhH[128 + j]; bf2 = bihF[128 + j] + bhhF[128 + j]; }
        else if (part == 2) { bh = bhhH[256 + j];                 bf2 = bhhF[256 + j]; }
        else                { bh = bihH[256 + j];                 bf2 = bihF[256 + j]; }
        barrH[idx] = bh; barrF[idx] = bf2;
    }
}

// ---------------------------------------------------------------------------
// Sparse edge list over adj: rec = (c1, c2, i, j) as float4 (order-invariant
// consumers, atomic append).
// ---------------------------------------------------------------------------
__global__ void prep_edges(const float* __restrict__ angles, const float* __restrict__ adj,
                           float4* __restrict__ edges, int* __restrict__ cnt) {
    int idx = blockIdx.x * 256 + threadIdx.x;
    if (idx < NN * NN && adj[idx] > 0.f) {
        float a = angles[idx];
        int pos = atomicAdd(cnt, 1);
        float4 r;
        r.x = cosf(a);
        r.y = cosf(a - 1.57079632679489662f);
        r.z = __int_as_float(idx / NN);   // i (source)
        r.w = __int_as_float(idx % NN);   // j (dest)
        edges[pos] = r;
    }
}

// ---------------------------------------------------------------------------
// Persistent fused kernel: one block per batch, 1024 threads (16 waves,
// 4 per SIMD). Wave (cg=w&7, rh=w>>3) owns h-cols [16cg,16cg+16) x row-half
// rh (6 row-tiles). h fp32 in registers (hreg[24]); h bf16 double-buffered
// in LDS; weights in VGPRs; fc B-fragment in LDS (zero-slot trick).
// ---------------------------------------------------------------------------
__global__ __launch_bounds__(NT) void fused_dgc(
    const float* __restrict__ feature,
    const float* __restrict__ pm25,
    const unsigned short* __restrict__ WaH, const float* __restrict__ barrH,
    const unsigned short* __restrict__ WaF, const float* __restrict__ barrF,
    const float* __restrict__ fchw, const float* __restrict__ fchb,
    const float* __restrict__ fcow, const float* __restrict__ fcob,
    const float* __restrict__ cw0, const float* __restrict__ cw1,
    const float* __restrict__ cbb,
    const float4* __restrict__ edges, const int* __restrict__ ecnt,
    float* __restrict__ pred)
{
    __shared__ unsigned short Ah[2][RPAD * STRH];   // 104,448 B
    __shared__ unsigned short Ax[RPAD * STRX];      //  15,360 B
    __shared__ unsigned short fcls[17 * 8];         //     272 B (slot 16 = zeros)
    __shared__ float xn_s[RPAD];
    __shared__ float fs[NN * FF];
    __shared__ unsigned long long maskT[NN][3];
    __shared__ int deg_s[NN];
    __shared__ float dinv_s[NN];
    __shared__ float hz_s[NN];

    const int tid = threadIdx.x;
    const int bb = blockIdx.x;
    const int w = tid >> 6, lane = tid & 63, q = lane >> 4, lq = lane & 15;
    const int cg = w & 7, rh = w >> 3;
    const int jcol = cg * 16 + lq;         // owned h-column, 0..127
    const int rt0 = rh * 6;                // first row-tile of this wave

    for (int i = tid; i < RPAD * STRH; i += NT) Ah[0][i] = 0;
    for (int i = tid; i < RPAD * STRX; i += NT) Ax[i] = 0;
    __syncthreads();
    if (tid < NN)
        Ax[tid * STRX + 1] = f2bf(pm25[(long)bb * TH * NN + tid]);   // p at t=0

    // ---- phase weights in registers (only nonzero chunks) ----
    bf16x8 wregH[3][4];   // g = R,Z,NH : kc 0..3 (h part)
    bf16x8 wregX[3];      // g = R,Z,NX : kc 4    (x part)
    float bias[4], fcb0;

    auto load_phase = [&](const unsigned short* Wa, const float* barr,
                          const float* fcw, const float* fcb) {
        #pragma unroll
        for (int g = 0; g < 3; ++g)
            #pragma unroll
            for (int kc = 0; kc < 4; ++kc)
                wregH[g][kc] = *(const bf16x8*)(Wa + (long)(g * 128 + jcol) * KA + kc * 32 + q * 8);
        wregX[0] = *(const bf16x8*)(Wa + (long)(0 * 128 + jcol) * KA + 128 + q * 8);
        wregX[1] = *(const bf16x8*)(Wa + (long)(1 * 128 + jcol) * KA + 128 + q * 8);
        wregX[2] = *(const bf16x8*)(Wa + (long)(3 * 128 + jcol) * KA + 128 + q * 8);
        #pragma unroll
        for (int g = 0; g < 4; ++g) bias[g] = barr[g * 128 + jcol];
        if (tid < 136) fcls[tid] = (tid < 128) ? f2bf(fcw[tid]) : (unsigned short)0;
        fcb0 = fcb[0];
    };
    load_phase(WaH, barrH, fchw, fchb);

    const int nE = *ecnt;

    float hreg[24];                        // fp32 h: rows rt0*16+rl*16+q*4+rg, col jcol
    #pragma unroll
    for (int i = 0; i < 24; ++i) hreg[i] = 0.f;

    int p = 0;

    for (int t = 0; t < TH + TF; ++t) {
        // ================= graph phase (fore steps only) =================
        if (t >= TH) {
            const float4* fb4 = (const float4*)(feature + ((long)bb * 48 + t) * (NN * FF));
            for (int i = tid; i < (NN * FF) / 4; i += NT) ((float4*)fs)[i] = fb4[i];
            for (int i = tid; i < NN * 3; i += NT) ((unsigned long long*)maskT)[i] = 0ull;
            for (int i = tid; i < NN; i += NT) deg_s[i] = 0;
            __syncthreads();
            for (int e = tid; e < nE; e += NT) {
                float4 rec = edges[e];
                int ii = __float_as_int(rec.z), jj = __float_as_int(rec.w);
                if (fs[ii * FF] * rec.x + fs[ii * FF + 1] * rec.y >= 0.5f) {
                    atomicAdd(&deg_s[ii], 1);
                    atomicOr(&maskT[jj][ii >> 6], 1ull << (ii & 63));
                }
            }
            __syncthreads();
            if (tid < NN) {
                int d = deg_s[tid];
                dinv_s[tid] = (d > 0) ? rsqrtf((float)d) : 0.f;
                hz_s[tid] = (d > 0) ? 0.f : -1.f;
                Ax[tid * STRX + 0] = f2bf(xn_s[tid]);
                #pragma unroll
                for (int c = 0; c < FF; ++c)
                    Ax[tid * STRX + 1 + c] = f2bf(fs[tid * FF + c]);
            }
            __syncthreads();
            if (tid < NN) {
                int j = tid;
                float w0r[9], w1r[9];
                #pragma unroll
                for (int c = 0; c < 9; ++c) { w0r[c] = cw0[c]; w1r[c] = cw1[c]; }
                float acc9[9];
                #pragma unroll
                for (int c = 0; c < 9; ++c) acc9[c] = 0.f;
                #pragma unroll
                for (int wd = 0; wd < 3; ++wd) {
                    unsigned long long m = maskT[j][wd];
                    while (m) {
                        int bp = __ffsll((unsigned long long)m) - 1;
                        m &= m - 1;
                        int i = wd * 64 + bp;
                        float d = dinv_s[i];
                        acc9[0] += d * xn_s[i];
                        #pragma unroll
                        for (int c = 1; c < 9; ++c) acc9[c] += d * fs[i * FF + c - 1];
                    }
                }
                float dj = dinv_s[j], hzj = hz_s[j];
                float gsum = cbb[0];
                #pragma unroll
                for (int c = 0; c < 9; ++c) {
                    float xv = (c == 0) ? xn_s[j] : fs[j * FF + c - 1];
                    float y = -dj * acc9[c] + hzj * xv;
                    gsum += xv * w0r[c] + y * w1r[c];
                }
                Ax[j * STRX + 9] = f2bf(sigmoidf_(gsum));
            }
            __syncthreads();
        }

        // ================= GRU GEMM + gate epilogue (6 row-tiles) =========
        #pragma unroll
        for (int rl = 0; rl < 6; ++rl) {
            const int rt = rt0 + rl;
            f32x4 a0 = {0.f,0.f,0.f,0.f}, a1 = {0.f,0.f,0.f,0.f}, a2 = {0.f,0.f,0.f,0.f};
            #pragma unroll
            for (int kc = 0; kc < 4; ++kc) {
                bf16x8 af = *(const bf16x8*)(&Ah[p][(rt * 16 + lq) * STRH + kc * 32 + q * 8]);
                a0 = __builtin_amdgcn_mfma_f32_16x16x32_bf16(af, wregH[0][kc], a0, 0, 0, 0);
                a1 = __builtin_amdgcn_mfma_f32_16x16x32_bf16(af, wregH[1][kc], a1, 0, 0, 0);
                a2 = __builtin_amdgcn_mfma_f32_16x16x32_bf16(af, wregH[2][kc], a2, 0, 0, 0);
            }
            bf16x8 ax = *(const bf16x8*)(&Ax[(rt * 16 + lq) * STRX + q * 8]);
            a0 = __builtin_amdgcn_mfma_f32_16x16x32_bf16(ax, wregX[0], a0, 0, 0, 0);
            a1 = __builtin_amdgcn_mfma_f32_16x16x32_bf16(ax, wregX[1], a1, 0, 0, 0);
            f32x4 a3 = {0.f,0.f,0.f,0.f};
            a3 = __builtin_amdgcn_mfma_f32_16x16x32_bf16(ax, wregX[2], a3, 0, 0, 0);
            #pragma unroll
            for (int rg = 0; rg < 4; ++rg) {
                int r = rt * 16 + q * 4 + rg;
                float rr  = sigmoidf_(a0[rg] + bias[0]);
                float zz  = sigmoidf_(a1[rg] + bias[1]);
                float nn2 = tanhf_(a3[rg] + bias[3] + rr * (a2[rg] + bias[2]));
                float hn = (1.f - zz) * nn2 + zz * hreg[rl * 4 + rg];
                hreg[rl * 4 + rg] = hn;
                Ah[p ^ 1][r * STRH + jcol] = f2bf(hn);
            }
        }
        __syncthreads();

        // ================= fc pass: xn = fcw . h_new via one-col MFMA =====
        if (w < 12) {
            const int rt = w;
            f32x4 fa = {0.f,0.f,0.f,0.f};
            #pragma unroll
            for (int kc = 0; kc < 4; ++kc) {
                bf16x8 af = *(const bf16x8*)(&Ah[p ^ 1][(rt * 16 + lq) * STRH + kc * 32 + q * 8]);
                int slot = (lq == 0) ? (kc * 4 + q) : 16;
                bf16x8 bfc = *(const bf16x8*)(&fcls[slot * 8]);
                fa = __builtin_amdgcn_mfma_f32_16x16x32_bf16(af, bfc, fa, 0, 0, 0);
            }
            int rbase = rt * 16 + q * 4;
            if (lq == 0 && rbase < NN) {
                float4 xn4;
                xn4.x = fa[0] + fcb0; xn4.y = fa[1] + fcb0;
                xn4.z = fa[2] + fcb0; xn4.w = fa[3] + fcb0;
                *(float4*)&xn_s[rbase] = xn4;
                if (t >= TH) {
                    *(float4*)(pred + ((long)bb * TF + (t - TH)) * NN + rbase) = xn4;
                } else if (t < TH - 1) {
                    float4 p4 = *(const float4*)(pm25 + ((long)bb * TH + t + 1) * NN + rbase);
                    Ax[(rbase + 0) * STRX + 0] = f2bf(xn4.x);
                    Ax[(rbase + 1) * STRX + 0] = f2bf(xn4.y);
                    Ax[(rbase + 2) * STRX + 0] = f2bf(xn4.z);
                    Ax[(rbase + 3) * STRX + 0] = f2bf(xn4.w);
                    Ax[(rbase + 0) * STRX + 1] = f2bf(p4.x);
                    Ax[(rbase + 1) * STRX + 1] = f2bf(p4.y);
                    Ax[(rbase + 2) * STRX + 1] = f2bf(p4.z);
                    Ax[(rbase + 3) * STRX + 1] = f2bf(p4.w);
                }
            }
        }
        __syncthreads();

        if (t == TH - 1)
            load_phase(WaF, barrF, fcow, fcob);
        p ^= 1;
    }
}

extern "C" void kernel_launch(void* const* d_in, const int* in_sizes, int n_in,
                              void* d_out, int out_size, void* d_ws, size_t ws_size,
                              hipStream_t stream) {
    const float* feature = (const float*)d_in[0];
    const float* pm25    = (const float*)d_in[1];
    const float* adj     = (const float*)d_in[2];
    const float* angles  = (const float*)d_in[3];
    const float* W_ih_h  = (const float*)d_in[4];
    const float* W_hh_h  = (const float*)d_in[5];
    const float* b_ih_h  = (const float*)d_in[6];
    const float* b_hh_h  = (const float*)d_in[7];
    const float* fch_w   = (const float*)d_in[8];
    const float* fch_b   = (const float*)d_in[9];
    const float* cw0     = (const float*)d_in[10];
    const float* cw1     = (const float*)d_in[11];
    const float* cbb     = (const float*)d_in[12];
    const float* W_ih    = (const float*)d_in[13];
    const float* W_hh    = (const float*)d_in[14];
    const float* b_ih    = (const float*)d_in[15];
    const float* b_hh    = (const float*)d_in[16];
    const float* fco_w   = (const float*)d_in[17];
    const float* fco_b   = (const float*)d_in[18];
    float* pred = (float*)d_out;

    char* ws = (char*)d_ws;
    size_t off = 0;
    unsigned short* WaH   = (unsigned short*)(ws + off); off += (size_t)NG * KA * 2;
    unsigned short* WaF   = (unsigned short*)(ws + off); off += (size_t)NG * KA * 2;
    float*          barrH = (float*)(ws + off);          off += (size_t)NG * 4;
    float*          barrF = (float*)(ws + off);          off += (size_t)NG * 4;
    float4*         edges = (float4*)(ws + off);         off += (size_t)NN * NN * 16;
    int*            cnt   = (int*)(ws + off);            off += 16;

    hipMemsetAsync(cnt, 0, 16, stream);
    prep_weights<<<(NG * KA + 255) / 256, 256, 0, stream>>>(
        W_hh_h, W_ih_h, W_hh, W_ih, b_ih_h, b_hh_h, b_ih, b_hh,
        WaH, WaF, barrH, barrF);
    prep_edges<<<(NN * NN + 255) / 256, 256, 0, stream>>>(angles, adj, edges, cnt);

    fused_dgc<<<BB, NT, 0, stream>>>(
        feature, pm25, WaH, barrH, WaF, barrF,
        fch_w, fch_b, fco_w, fco_b, cw0, cw1, cbb,
        edges, cnt, pred);
}

// Round 7
// 963.651 us; speedup vs baseline: 1.0930x; 1.0930x over previous
//
#include <hip/hip_runtime.h>
#include <math.h>

#define BB 256
#define NN 184
#define HH 128
#define FF 8
#define TH 24
#define TF 24
#define KA 160       // augmented K (128 h + x block + pad; k=139 = bias col)
#define NG 512       // 4 gate-parts x 128
#define RPAD 192     // padded row count (12 tiles of 16)
#define STRH 136     // Ah row stride (elems)
#define STRX 40      // Ax row stride (elems)
#define NT 1024      // threads per block (16 waves, 4/SIMD)

typedef __attribute__((ext_vector_type(8))) short bf16x8;
typedef __attribute__((ext_vector_type(4))) float f32x4;
typedef __attribute__((ext_vector_type(2))) unsigned u32x2;

__device__ __forceinline__ float sigmoidf_(float x) {
    return 1.0f / (1.0f + __expf(-x));
}
__device__ __forceinline__ float tanhf_(float x) {
    float s = (x >= 0.f) ? 1.f : -1.f;
    float e = __expf(-2.0f * fabsf(x));
    return s * (1.0f - e) / (1.0f + e);
}
__device__ __forceinline__ unsigned short f2bf(float f) {
    unsigned u = __float_as_uint(f);
    u += 0x7fffu + ((u >> 16) & 1u);
    return (unsigned short)(u >> 16);
}

// ---------------------------------------------------------------------------
// Augmented bf16 weights Wa[512][160] (R, Z, NH, NX). Biases for R/Z/NX are
// folded into column k=139 (paired with const-1 in Ax[.][11]). NH bias (used
// inside r*(hnn+b)) stays in barr[2*128 + j].
// ---------------------------------------------------------------------------
__global__ void prep_weights(const float* __restrict__ WhhH, const float* __restrict__ WihH,
                             const float* __restrict__ WhhF, const float* __restrict__ WihF,
                             const float* __restrict__ bihH, const float* __restrict__ bhhH,
                             const float* __restrict__ bihF, const float* __restrict__ bhhF,
                             unsigned short* __restrict__ WaH, unsigned short* __restrict__ WaF,
                             float* __restrict__ barrH, float* __restrict__ barrF) {
    int idx = blockIdx.x * 256 + threadIdx.x;
    if (idx < NG * KA) {
        int jp = idx / KA, k = idx % KA;
        int j = jp & 127, part = jp >> 7;
        float vh = 0.f, vf = 0.f;
        if (part <= 1) {              // R, Z: combined Whh | Wih | bias@139
            int row = part * 128 + j;
            if (k < 128) { vh = WhhH[row * 128 + k]; vf = WhhF[row * 128 + k]; }
            else {
                if (k < 130) vh = WihH[row * 2 + (k - 128)];
                if (k < 138) vf = WihF[row * 10 + (k - 128)];
                if (k == 139) { vh = bihH[row] + bhhH[row]; vf = bihF[row] + bhhF[row]; }
            }
        } else if (part == 2) {       // NH: h part of n-gate (no bias fold)
            if (k < 128) { vh = WhhH[(256 + j) * 128 + k]; vf = WhhF[(256 + j) * 128 + k]; }
        } else {                      // NX: x part of n-gate | bih@139
            if (k >= 128) {
                if (k < 130) vh = WihH[(256 + j) * 2 + (k - 128)];
                if (k < 138) vf = WihF[(256 + j) * 10 + (k - 128)];
                if (k == 139) { vh = bihH[256 + j]; vf = bihF[256 + j]; }
            }
        }
        WaH[idx] = f2bf(vh); WaF[idx] = f2bf(vf);
    }
    if (idx < NG) {
        int j = idx & 127, part = idx >> 7;
        float bh, bf2;
        if (part == 0)      { bh = bihH[j] + bhhH[j];             bf2 = bihF[j] + bhhF[j]; }
        else if (part == 1) { bh = bihH[128 + j] + bhhH[128 + j]; bf2 = bihF[128 + j] + bhhF[128 + j]; }
        else if (part == 2) { bh = bhhH[256 + j];                 bf2 = bhhF[256 + j]; }
        else                { bh = bihH[256 + j];                 bf2 = bihF[256 + j]; }
        barrH[idx] = bh; barrF[idx] = bf2;
    }
}

// ---------------------------------------------------------------------------
// Sparse edge list over adj: rec = (c1, c2, i, j) as float4 (order-invariant
// consumers, atomic append).
// ---------------------------------------------------------------------------
__global__ void prep_edges(const float* __restrict__ angles, const float* __restrict__ adj,
                           float4* __restrict__ edges, int* __restrict__ cnt) {
    int idx = blockIdx.x * 256 + threadIdx.x;
    if (idx < NN * NN && adj[idx] > 0.f) {
        float a = angles[idx];
        int pos = atomicAdd(cnt, 1);
        float4 r;
        r.x = cosf(a);
        r.y = cosf(a - 1.57079632679489662f);
        r.z = __int_as_float(idx / NN);   // i (source)
        r.w = __int_as_float(idx % NN);   // j (dest)
        edges[pos] = r;
    }
}

// ---------------------------------------------------------------------------
// Persistent fused kernel: one block per batch, 1024 threads (16 waves,
// 4/SIMD). OPERAND-SWAPPED MFMA: A = weights (in VGPRs), B = h (LDS).
// D[m=gatecol][n=row] -> thread owns 4 consecutive h-cols of one row ->
// packed b64 LDS writes. Wave (cg=w&7, rh=w>>3): cols [16cg,16cg+16),
// row-tiles [6rh, 6rh+6). h fp32 in hreg[24].
// ---------------------------------------------------------------------------
__global__ __launch_bounds__(NT, 4) void fused_dgc(
    const float* __restrict__ feature,
    const float* __restrict__ pm25,
    const unsigned short* __restrict__ WaH, const float* __restrict__ barrH,
    const unsigned short* __restrict__ WaF, const float* __restrict__ barrF,
    const float* __restrict__ fchw, const float* __restrict__ fchb,
    const float* __restrict__ fcow, const float* __restrict__ fcob,
    const float* __restrict__ cw0, const float* __restrict__ cw1,
    const float* __restrict__ cbb,
    const float4* __restrict__ edges, const int* __restrict__ ecnt,
    float* __restrict__ pred)
{
    __shared__ unsigned short Ah[2][RPAD * STRH];   // 104,448 B
    __shared__ unsigned short Ax[RPAD * STRX];      //  15,360 B
    __shared__ unsigned short fcls[17 * 8];         //     272 B (slot 16 = zeros)
    __shared__ float xn_s[RPAD];
    __shared__ float fs[NN * FF];
    __shared__ unsigned long long maskT[NN][3];
    __shared__ int deg_s[NN];
    __shared__ float dinv_s[NN];
    __shared__ float hz_s[NN];

    const int tid = threadIdx.x;
    const int bb = blockIdx.x;
    const int w = tid >> 6, lane = tid & 63, q = lane >> 4, lq = lane & 15;
    const int cg = w & 7, rh = w >> 3;
    const int rt0 = rh * 6;                // first row-tile of this wave

    for (int i = tid; i < RPAD * STRH; i += NT) Ah[0][i] = 0;
    for (int i = tid; i < RPAD * STRX; i += NT) Ax[i] = 0;
    __syncthreads();
    if (tid < RPAD) Ax[tid * STRX + 11] = (unsigned short)0x3F80;   // const 1.0
    if (tid < NN)
        Ax[tid * STRX + 1] = f2bf(pm25[(long)bb * TH * NN + tid]);  // p at t=0

    // ---- phase weights in registers (A-operand fragments) ----
    bf16x8 wregH[3][4];   // g = R,Z,NH : kc 0..3 (h part)
    bf16x8 wregX[3];      // g = R,Z,NX : kc 4    (x part, incl. bias col)
    float bias2[4], fcb0; // NH bias for the thread's 4 cols

    auto load_phase = [&](const unsigned short* Wa, const float* barr,
                          const float* fcw, const float* fcb) {
        const int jcol = cg * 16 + lq;
        #pragma unroll
        for (int g = 0; g < 3; ++g)
            #pragma unroll
            for (int kc = 0; kc < 4; ++kc)
                wregH[g][kc] = *(const bf16x8*)(Wa + (long)(g * 128 + jcol) * KA + kc * 32 + q * 8);
        wregX[0] = *(const bf16x8*)(Wa + (long)(0 * 128 + jcol) * KA + 128 + q * 8);
        wregX[1] = *(const bf16x8*)(Wa + (long)(1 * 128 + jcol) * KA + 128 + q * 8);
        wregX[2] = *(const bf16x8*)(Wa + (long)(3 * 128 + jcol) * KA + 128 + q * 8);
        #pragma unroll
        for (int rg = 0; rg < 4; ++rg)
            bias2[rg] = barr[2 * 128 + cg * 16 + q * 4 + rg];
        if (tid < 136) fcls[tid] = (tid < 128) ? f2bf(fcw[tid]) : (unsigned short)0;
        fcb0 = fcb[0];
    };
    load_phase(WaH, barrH, fchw, fchb);

    const int nE = *ecnt;

    float hreg[24];        // fp32 h: row rt0*16+rl*16+lq (per rl), cols 16cg+4q+rg
    #pragma unroll
    for (int i = 0; i < 24; ++i) hreg[i] = 0.f;

    int p = 0;
    __syncthreads();       // Ax init visible to all GEMM readers

    for (int t = 0; t < TH + TF; ++t) {
        // ================= graph phase (fore steps only) =================
        if (t >= TH) {
            const float4* fb4 = (const float4*)(feature + ((long)bb * 48 + t) * (NN * FF));
            for (int i = tid; i < (NN * FF) / 4; i += NT) ((float4*)fs)[i] = fb4[i];
            for (int i = tid; i < NN * 3; i += NT) ((unsigned long long*)maskT)[i] = 0ull;
            for (int i = tid; i < NN; i += NT) deg_s[i] = 0;
            __syncthreads();
            for (int e = tid; e < nE; e += NT) {
                float4 rec = edges[e];
                int ii = __float_as_int(rec.z), jj = __float_as_int(rec.w);
                if (fs[ii * FF] * rec.x + fs[ii * FF + 1] * rec.y >= 0.5f) {
                    atomicAdd(&deg_s[ii], 1);
                    atomicOr(&maskT[jj][ii >> 6], 1ull << (ii & 63));
                }
            }
            __syncthreads();
            if (tid < NN) {
                int d = deg_s[tid];
                dinv_s[tid] = (d > 0) ? rsqrtf((float)d) : 0.f;
                hz_s[tid] = (d > 0) ? 0.f : -1.f;
                Ax[tid * STRX + 0] = f2bf(xn_s[tid]);
                #pragma unroll
                for (int c = 0; c < FF; ++c)
                    Ax[tid * STRX + 1 + c] = f2bf(fs[tid * FF + c]);
            }
            __syncthreads();
            if (tid < NN) {
                int j = tid;
                float w0r[9], w1r[9];
                #pragma unroll
                for (int c = 0; c < 9; ++c) { w0r[c] = cw0[c]; w1r[c] = cw1[c]; }
                float acc9[9];
                #pragma unroll
                for (int c = 0; c < 9; ++c) acc9[c] = 0.f;
                #pragma unroll
                for (int wd = 0; wd < 3; ++wd) {
                    unsigned long long m = maskT[j][wd];
                    while (m) {
                        int bp = __ffsll((unsigned long long)m) - 1;
                        m &= m - 1;
                        int i = wd * 64 + bp;
                        float d = dinv_s[i];
                        acc9[0] += d * xn_s[i];
                        #pragma unroll
                        for (int c = 1; c < 9; ++c) acc9[c] += d * fs[i * FF + c - 1];
                    }
                }
                float dj = dinv_s[j], hzj = hz_s[j];
                float gsum = cbb[0];
                #pragma unroll
                for (int c = 0; c < 9; ++c) {
                    float xv = (c == 0) ? xn_s[j] : fs[j * FF + c - 1];
                    float y = -dj * acc9[c] + hzj * xv;
                    gsum += xv * w0r[c] + y * w1r[c];
                }
                Ax[j * STRX + 9] = f2bf(sigmoidf_(gsum));
            }
            __syncthreads();
        }

        // ========== GRU GEMM (A=weights, B=h) + epilogue, 6 row-tiles ======
        #pragma unroll
        for (int rl = 0; rl < 6; ++rl) {
            const int rt = rt0 + rl;
            f32x4 a0 = {0.f,0.f,0.f,0.f}, a1 = {0.f,0.f,0.f,0.f}, a2 = {0.f,0.f,0.f,0.f};
            #pragma unroll
            for (int kc = 0; kc < 4; ++kc) {
                bf16x8 bh = *(const bf16x8*)(&Ah[p][(rt * 16 + lq) * STRH + kc * 32 + q * 8]);
                a0 = __builtin_amdgcn_mfma_f32_16x16x32_bf16(wregH[0][kc], bh, a0, 0, 0, 0);
                a1 = __builtin_amdgcn_mfma_f32_16x16x32_bf16(wregH[1][kc], bh, a1, 0, 0, 0);
                a2 = __builtin_amdgcn_mfma_f32_16x16x32_bf16(wregH[2][kc], bh, a2, 0, 0, 0);
            }
            bf16x8 bx = *(const bf16x8*)(&Ax[(rt * 16 + lq) * STRX + q * 8]);
            a0 = __builtin_amdgcn_mfma_f32_16x16x32_bf16(wregX[0], bx, a0, 0, 0, 0);
            a1 = __builtin_amdgcn_mfma_f32_16x16x32_bf16(wregX[1], bx, a1, 0, 0, 0);
            f32x4 a3 = {0.f,0.f,0.f,0.f};
            a3 = __builtin_amdgcn_mfma_f32_16x16x32_bf16(wregX[2], bx, a3, 0, 0, 0);

            float hn[4];
            #pragma unroll
            for (int rg = 0; rg < 4; ++rg) {
                float rr  = sigmoidf_(a0[rg]);                       // bias folded
                float zz  = sigmoidf_(a1[rg]);
                float nn2 = tanhf_(a3[rg] + rr * (a2[rg] + bias2[rg]));
                float hv  = (1.f - zz) * nn2 + zz * hreg[rl * 4 + rg];
                hreg[rl * 4 + rg] = hv;
                hn[rg] = hv;
            }
            unsigned u0 = (unsigned)f2bf(hn[0]) | ((unsigned)f2bf(hn[1]) << 16);
            unsigned u1 = (unsigned)f2bf(hn[2]) | ((unsigned)f2bf(hn[3]) << 16);
            u32x2 pk; pk[0] = u0; pk[1] = u1;
            *(u32x2*)&Ah[p ^ 1][(rt * 16 + lq) * STRH + cg * 16 + q * 4] = pk;
        }
        __syncthreads();

        // ========== fc pass: xn = fcw . h_new (A=fc row, B=h) ==============
        if (w < 12) {
            const int rt = w;
            f32x4 fa = {0.f,0.f,0.f,0.f};
            #pragma unroll
            for (int kc = 0; kc < 4; ++kc) {
                bf16x8 bh = *(const bf16x8*)(&Ah[p ^ 1][(rt * 16 + lq) * STRH + kc * 32 + q * 8]);
                int slot = (lq == 0) ? (kc * 4 + q) : 16;
                bf16x8 afc = *(const bf16x8*)(&fcls[slot * 8]);
                fa = __builtin_amdgcn_mfma_f32_16x16x32_bf16(afc, bh, fa, 0, 0, 0);
            }
            int row = rt * 16 + lq;
            if (q == 0 && row < NN) {       // D[m=0][n=row] lives in q==0, reg 0
                float xn = fa[0] + fcb0;
                xn_s[row] = xn;
                if (t >= TH) {
                    pred[((long)bb * TF + (t - TH)) * NN + row] = xn;
                } else if (t < TH - 1) {
                    Ax[row * STRX + 0] = f2bf(xn);
                    Ax[row * STRX + 1] = f2bf(pm25[((long)bb * TH + t + 1) * NN + row]);
                }
            }
        }
        __syncthreads();

        if (t == TH - 1)
            load_phase(WaF, barrF, fcow, fcob);
        p ^= 1;
    }
}

extern "C" void kernel_launch(void* const* d_in, const int* in_sizes, int n_in,
                              void* d_out, int out_size, void* d_ws, size_t ws_size,
                              hipStream_t stream) {
    const float* feature = (const float*)d_in[0];
    const float* pm25    = (const float*)d_in[1];
    const float* adj     = (const float*)d_in[2];
    const float* angles  = (const float*)d_in[3];
    const float* W_ih_h  = (const float*)d_in[4];
    const float* W_hh_h  = (const float*)d_in[5];
    const float* b_ih_h  = (const float*)d_in[6];
    const float* b_hh_h  = (const float*)d_in[7];
    const float* fch_w   = (const float*)d_in[8];
    const float* fch_b   = (const float*)d_in[9];
    const float* cw0     = (const float*)d_in[10];
    const float* cw1     = (const float*)d_in[11];
    const float* cbb     = (const float*)d_in[12];
    const float* W_ih    = (const float*)d_in[13];
    const float* W_hh    = (const float*)d_in[14];
    const float* b_ih    = (const float*)d_in[15];
    const float* b_hh    = (const float*)d_in[16];
    const float* fco_w   = (const float*)d_in[17];
    const float* fco_b   = (const float*)d_in[18];
    float* pred = (float*)d_out;

    char* ws = (char*)d_ws;
    size_t off = 0;
    unsigned short* WaH   = (unsigned short*)(ws + off); off += (size_t)NG * KA * 2;
    unsigned short* WaF   = (unsigned short*)(ws + off); off += (size_t)NG * KA * 2;
    float*          barrH = (float*)(ws + off);          off += (size_t)NG * 4;
    float*          barrF = (float*)(ws + off);          off += (size_t)NG * 4;
    float4*         edges = (float4*)(ws + off);         off += (size_t)NN * NN * 16;
    int*            cnt   = (int*)(ws + off);            off += 16;

    hipMemsetAsync(cnt, 0, 16, stream);
    prep_weights<<<(NG * KA + 255) / 256, 256, 0, stream>>>(
        W_hh_h, W_ih_h, W_hh, W_ih, b_ih_h, b_hh_h, b_ih, b_hh,
        WaH, WaF, barrH, barrF);
    prep_edges<<<(NN * NN + 255) / 256, 256, 0, stream>>>(angles, adj, edges, cnt);

    fused_dgc<<<BB, NT, 0, stream>>>(
        feature, pm25, WaH, barrH, WaF, barrF,
        fch_w, fch_b, fco_w, fco_b, cw0, cw1, cbb,
        edges, cnt, pred);
}

// Round 8
// 894.043 us; speedup vs baseline: 1.1781x; 1.0779x over previous
//
#include <hip/hip_runtime.h>
#include <hip/hip_bf16.h>
#include <math.h>

#define BB 256
#define NN 184
#define HH 128
#define FF 8
#define TH 24
#define TF 24
#define KA 160       // augmented K (128 h + x block + pad; k=139 = bias col)
#define NG 512       // 4 gate-parts x 128
#define RPAD 192     // padded row count (12 tiles of 16)
#define STRH 136     // Ah row stride (elems)
#define STRX 40      // Ax row stride (elems)
#define NT 1024      // threads per block (16 waves, 4/SIMD)

typedef __attribute__((ext_vector_type(8))) short bf16x8;
typedef __attribute__((ext_vector_type(4))) float f32x4;
typedef __attribute__((ext_vector_type(2))) unsigned u32x2;

__device__ __forceinline__ float sigmoidf_(float x) {
    return 1.0f / (1.0f + __expf(-x));
}
__device__ __forceinline__ float tanhf_(float x) {
    float s = (x >= 0.f) ? 1.f : -1.f;
    float e = __expf(-2.0f * fabsf(x));
    return s * (1.0f - e) / (1.0f + e);
}
__device__ __forceinline__ unsigned short f2bf(float f) {
    unsigned u = __float_as_uint(f);
    u += 0x7fffu + ((u >> 16) & 1u);
    return (unsigned short)(u >> 16);
}
__device__ __forceinline__ unsigned pkbf(float a, float b) {
    __hip_bfloat162 h = __float22bfloat162_rn(make_float2(a, b));
    return *reinterpret_cast<unsigned*>(&h);
}

// ---------------------------------------------------------------------------
// Augmented bf16 weights Wa[512][160] (R, Z, NH, NX). Biases for R/Z/NX are
// folded into column k=139 (paired with const-1 in Ax[.][11]). NH bias (used
// inside r*(hnn+b)) stays in barr[2*128 + j].
// ---------------------------------------------------------------------------
__global__ void prep_weights(const float* __restrict__ WhhH, const float* __restrict__ WihH,
                             const float* __restrict__ WhhF, const float* __restrict__ WihF,
                             const float* __restrict__ bihH, const float* __restrict__ bhhH,
                             const float* __restrict__ bihF, const float* __restrict__ bhhF,
                             unsigned short* __restrict__ WaH, unsigned short* __restrict__ WaF,
                             float* __restrict__ barrH, float* __restrict__ barrF) {
    int idx = blockIdx.x * 256 + threadIdx.x;
    if (idx < NG * KA) {
        int jp = idx / KA, k = idx % KA;
        int j = jp & 127, part = jp >> 7;
        float vh = 0.f, vf = 0.f;
        if (part <= 1) {              // R, Z: combined Whh | Wih | bias@139
            int row = part * 128 + j;
            if (k < 128) { vh = WhhH[row * 128 + k]; vf = WhhF[row * 128 + k]; }
            else {
                if (k < 130) vh = WihH[row * 2 + (k - 128)];
                if (k < 138) vf = WihF[row * 10 + (k - 128)];
                if (k == 139) { vh = bihH[row] + bhhH[row]; vf = bihF[row] + bhhF[row]; }
            }
        } else if (part == 2) {       // NH: h part of n-gate (no bias fold)
            if (k < 128) { vh = WhhH[(256 + j) * 128 + k]; vf = WhhF[(256 + j) * 128 + k]; }
        } else {                      // NX: x part of n-gate | bih@139
            if (k >= 128) {
                if (k < 130) vh = WihH[(256 + j) * 2 + (k - 128)];
                if (k < 138) vf = WihF[(256 + j) * 10 + (k - 128)];
                if (k == 139) { vh = bihH[256 + j]; vf = bihF[256 + j]; }
            }
        }
        WaH[idx] = f2bf(vh); WaF[idx] = f2bf(vf);
    }
    if (idx < NG) {
        int j = idx & 127, part = idx >> 7;
        float bh, bf2;
        if (part == 0)      { bh = bihH[j] + bhhH[j];             bf2 = bihF[j] + bhhF[j]; }
        else if (part == 1) { bh = bihH[128 + j] + bhhH[128 + j]; bf2 = bihF[128 + j] + bhhF[128 + j]; }
        else if (part == 2) { bh = bhhH[256 + j];                 bf2 = bhhF[256 + j]; }
        else                { bh = bihH[256 + j];                 bf2 = bihF[256 + j]; }
        barrH[idx] = bh; barrF[idx] = bf2;
    }
}

// ---------------------------------------------------------------------------
// Sparse edge list over adj: rec = (c1, c2, i, j) as float4 (order-invariant
// consumers, atomic append).
// ---------------------------------------------------------------------------
__global__ void prep_edges(const float* __restrict__ angles, const float* __restrict__ adj,
                           float4* __restrict__ edges, int* __restrict__ cnt) {
    int idx = blockIdx.x * 256 + threadIdx.x;
    if (idx < NN * NN && adj[idx] > 0.f) {
        float a = angles[idx];
        int pos = atomicAdd(cnt, 1);
        float4 r;
        r.x = cosf(a);
        r.y = cosf(a - 1.57079632679489662f);
        r.z = __int_as_float(idx / NN);   // i (source)
        r.w = __int_as_float(idx % NN);   // j (dest)
        edges[pos] = r;
    }
}

// ---------------------------------------------------------------------------
// Per-(batch, fore-step) graph precompute: wind-gated bitmask (dest-major),
// dinv, and G[j] = cheb gate pre-activation contribution of the 8 feature
// channels (+ cheb bias). Only the xn channel remains recurrent.
// ---------------------------------------------------------------------------
__global__ __launch_bounds__(256) void prep_graph(
    const float* __restrict__ feature,
    const float4* __restrict__ edges, const int* __restrict__ ecnt,
    const float* __restrict__ cw0, const float* __restrict__ cw1,
    const float* __restrict__ cbb,
    unsigned long long* __restrict__ maskG,   // [B*TF][NN*3]
    float* __restrict__ dinvG,                // [B*TF][NN]
    float* __restrict__ GG)                   // [B*TF][NN]
{
    const int bt = blockIdx.x;
    const int b = bt / TF, t = bt % TF;
    const int tid = threadIdx.x;
    __shared__ float f8[NN * FF];
    __shared__ unsigned long long mT[NN][3];
    __shared__ int dg[NN];
    __shared__ float di[NN];

    const float4* fb4 = (const float4*)(feature + ((long)b * 48 + TH + t) * (NN * FF));
    for (int i = tid; i < (NN * FF) / 4; i += 256) ((float4*)f8)[i] = fb4[i];
    for (int i = tid; i < NN * 3; i += 256) ((unsigned long long*)mT)[i] = 0ull;
    for (int i = tid; i < NN; i += 256) dg[i] = 0;
    __syncthreads();
    const int nE = *ecnt;
    for (int e = tid; e < nE; e += 256) {
        float4 rec = edges[e];
        int ii = __float_as_int(rec.z), jj = __float_as_int(rec.w);
        if (f8[ii * FF] * rec.x + f8[ii * FF + 1] * rec.y >= 0.5f) {
            atomicAdd(&dg[ii], 1);
            atomicOr(&mT[jj][ii >> 6], 1ull << (ii & 63));
        }
    }
    __syncthreads();
    if (tid < NN) di[tid] = (dg[tid] > 0) ? rsqrtf((float)dg[tid]) : 0.f;
    __syncthreads();
    if (tid < NN) {
        int j = tid;
        float acc[8];
        #pragma unroll
        for (int c = 0; c < 8; ++c) acc[c] = 0.f;
        #pragma unroll
        for (int wd = 0; wd < 3; ++wd) {
            unsigned long long m = mT[j][wd];
            while (m) {
                int bp = __ffsll(m) - 1; m &= m - 1;
                int i = wd * 64 + bp;
                float d = di[i];
                #pragma unroll
                for (int c = 0; c < 8; ++c) acc[c] += d * f8[i * FF + c];
            }
        }
        float dj = di[j];
        float hzj = (dj > 0.f) ? 0.f : -1.f;
        float G = cbb[0];
        #pragma unroll
        for (int c = 0; c < 8; ++c) {
            float xv = f8[j * FF + c];
            float y = -dj * acc[c] + hzj * xv;
            G += xv * cw0[c + 1] + y * cw1[c + 1];
        }
        GG[(long)bt * NN + j] = G;
        dinvG[(long)bt * NN + j] = dj;
        #pragma unroll
        for (int wd = 0; wd < 3; ++wd)
            maskG[((long)bt * NN + j) * 3 + wd] = mT[j][wd];
    }
}

// ---------------------------------------------------------------------------
// Persistent fused kernel: one block per batch, 1024 threads (16 waves,
// 4/SIMD). A = weights (VGPRs), B = h (LDS, double-buffered). Per fore step:
// cheb (xn channel only, precomputed mask/dinv/G) -> B -> GEMM -> B ->
// {fc || stage t+1} -> B. Hist: GEMM -> B -> fc -> B.
// ---------------------------------------------------------------------------
__global__ __launch_bounds__(NT, 4) void fused_dgc(
    const float* __restrict__ feature,
    const float* __restrict__ pm25,
    const unsigned short* __restrict__ WaH, const float* __restrict__ barrH,
    const unsigned short* __restrict__ WaF, const float* __restrict__ barrF,
    const float* __restrict__ fchw, const float* __restrict__ fchb,
    const float* __restrict__ fcow, const float* __restrict__ fcob,
    const float* __restrict__ cw0, const float* __restrict__ cw1,
    const unsigned long long* __restrict__ maskG,
    const float* __restrict__ dinvG, const float* __restrict__ GG,
    float* __restrict__ pred)
{
    __shared__ unsigned short Ah[2][RPAD * STRH];   // 104,448 B
    __shared__ unsigned short Ax[RPAD * STRX];      //  15,360 B
    __shared__ unsigned short fcls[17 * 8];         //     272 B (slot 16 = zeros)
    __shared__ float xn_s[RPAD];
    __shared__ unsigned long long maskL[NN * 3];    //   4,416 B
    __shared__ float dinv_s[NN];
    __shared__ float G_s[NN];

    const int tid = threadIdx.x;
    const int bb = blockIdx.x;
    const int w = tid >> 6, lane = tid & 63, q = lane >> 4, lq = lane & 15;
    const int cg = w & 7, rh = w >> 3;
    const int rt0 = rh * 6;                // first row-tile of this wave

    for (int i = tid; i < RPAD * STRH; i += NT) Ah[0][i] = 0;
    for (int i = tid; i < RPAD * STRX; i += NT) Ax[i] = 0;
    __syncthreads();
    if (tid < RPAD) Ax[tid * STRX + 11] = (unsigned short)0x3F80;   // const 1.0
    if (tid < NN)
        Ax[tid * STRX + 1] = f2bf(pm25[(long)bb * TH * NN + tid]);  // p at t=0

    // ---- phase weights in registers (A-operand fragments) ----
    bf16x8 wregH[3][4];   // g = R,Z,NH : kc 0..3 (h part)
    bf16x8 wregX[3];      // g = R,Z,NX : kc 4    (x part, incl. bias col)
    float bias2[4], fcb0; // NH bias for the thread's 4 cols

    auto load_phase = [&](const unsigned short* Wa, const float* barr,
                          const float* fcw, const float* fcb) {
        const int jcol = cg * 16 + lq;
        #pragma unroll
        for (int g = 0; g < 3; ++g)
            #pragma unroll
            for (int kc = 0; kc < 4; ++kc)
                wregH[g][kc] = *(const bf16x8*)(Wa + (long)(g * 128 + jcol) * KA + kc * 32 + q * 8);
        wregX[0] = *(const bf16x8*)(Wa + (long)(0 * 128 + jcol) * KA + 128 + q * 8);
        wregX[1] = *(const bf16x8*)(Wa + (long)(1 * 128 + jcol) * KA + 128 + q * 8);
        wregX[2] = *(const bf16x8*)(Wa + (long)(3 * 128 + jcol) * KA + 128 + q * 8);
        #pragma unroll
        for (int rg = 0; rg < 4; ++rg)
            bias2[rg] = barr[2 * 128 + cg * 16 + q * 4 + rg];
        if (tid < 136) fcls[tid] = (tid < 128) ? f2bf(fcw[tid]) : (unsigned short)0;
        fcb0 = fcb[0];
    };
    load_phase(WaH, barrH, fchw, fchb);

    const float w00 = cw0[0], w10 = cw1[0];

    float hreg[24];        // fp32 h: row rt*16+lq, cols 16cg+4q+rg
    #pragma unroll
    for (int i = 0; i < 24; ++i) hreg[i] = 0.f;

    int p = 0;
    __syncthreads();       // Ax/fcls init visible

    for (int t = 0; t < TH + TF; ++t) {
        // ============ cheb gate (fore steps; xn channel only) =============
        if (t >= TH) {
            if (tid < NN) {
                int j = tid;
                float xnj = xn_s[j];
                float acc = 0.f;
                #pragma unroll
                for (int wd = 0; wd < 3; ++wd) {
                    unsigned long long m = maskL[j * 3 + wd];
                    while (m) {
                        int bp = __ffsll(m) - 1; m &= m - 1;
                        int i = wd * 64 + bp;
                        acc += dinv_s[i] * xn_s[i];
                    }
                }
                float dj = dinv_s[j];
                float hzj = (dj > 0.f) ? 0.f : -1.f;
                float y0 = -dj * acc + hzj * xnj;
                float g = sigmoidf_(G_s[j] + xnj * w00 + y0 * w10);
                Ax[j * STRX + 9] = f2bf(g);
                Ax[j * STRX + 0] = f2bf(xnj);
            }
            __syncthreads();
        }

        // ========== GRU GEMM (A=weights, B=h) + epilogue, 6 row-tiles ======
        #pragma unroll
        for (int rl = 0; rl < 6; ++rl) {
            const int rt = rt0 + rl;
            f32x4 a0 = {0.f,0.f,0.f,0.f}, a1 = {0.f,0.f,0.f,0.f}, a2 = {0.f,0.f,0.f,0.f};
            #pragma unroll
            for (int kc = 0; kc < 4; ++kc) {
                bf16x8 bh = *(const bf16x8*)(&Ah[p][(rt * 16 + lq) * STRH + kc * 32 + q * 8]);
                a0 = __builtin_amdgcn_mfma_f32_16x16x32_bf16(wregH[0][kc], bh, a0, 0, 0, 0);
                a1 = __builtin_amdgcn_mfma_f32_16x16x32_bf16(wregH[1][kc], bh, a1, 0, 0, 0);
                a2 = __builtin_amdgcn_mfma_f32_16x16x32_bf16(wregH[2][kc], bh, a2, 0, 0, 0);
            }
            bf16x8 bx = *(const bf16x8*)(&Ax[(rt * 16 + lq) * STRX + q * 8]);
            a0 = __builtin_amdgcn_mfma_f32_16x16x32_bf16(wregX[0], bx, a0, 0, 0, 0);
            a1 = __builtin_amdgcn_mfma_f32_16x16x32_bf16(wregX[1], bx, a1, 0, 0, 0);
            f32x4 a3 = {0.f,0.f,0.f,0.f};
            a3 = __builtin_amdgcn_mfma_f32_16x16x32_bf16(wregX[2], bx, a3, 0, 0, 0);

            float hn[4];
            #pragma unroll
            for (int rg = 0; rg < 4; ++rg) {
                float rr  = sigmoidf_(a0[rg]);                       // bias folded
                float zz  = sigmoidf_(a1[rg]);
                float nn2 = tanhf_(a3[rg] + rr * (a2[rg] + bias2[rg]));
                float hv  = (1.f - zz) * nn2 + zz * hreg[rl * 4 + rg];
                hreg[rl * 4 + rg] = hv;
                hn[rg] = hv;
            }
            u32x2 pk;
            pk[0] = pkbf(hn[0], hn[1]);
            pk[1] = pkbf(hn[2], hn[3]);
            *(u32x2*)&Ah[p ^ 1][(rt * 16 + lq) * STRH + cg * 16 + q * 4] = pk;
        }
        __syncthreads();

        // ========== merged: fc (waves 0-11) || stage t+1 (waves 12-15) =====
        if (w < 12) {
            const int rt = w;
            f32x4 fa = {0.f,0.f,0.f,0.f};
            #pragma unroll
            for (int kc = 0; kc < 4; ++kc) {
                bf16x8 bh = *(const bf16x8*)(&Ah[p ^ 1][(rt * 16 + lq) * STRH + kc * 32 + q * 8]);
                int slot = (lq == 0) ? (kc * 4 + q) : 16;
                bf16x8 afc = *(const bf16x8*)(&fcls[slot * 8]);
                fa = __builtin_amdgcn_mfma_f32_16x16x32_bf16(afc, bh, fa, 0, 0, 0);
            }
            int row = rt * 16 + lq;
            if (q == 0 && row < NN) {       // D[m=0][n=row] lives in q==0, reg 0
                float xn = fa[0] + fcb0;
                xn_s[row] = xn;
                if (t >= TH) {
                    pred[((long)bb * TF + (t - TH)) * NN + row] = xn;
                } else if (t < TH - 1) {
                    Ax[row * STRX + 0] = f2bf(xn);
                    Ax[row * STRX + 1] = f2bf(pm25[((long)bb * TH + t + 1) * NN + row]);
                }
            }
        } else {
            const int s = tid - 768;       // 0..255
            const int t2 = t + 1;
            if (t2 >= TH && t2 < TH + TF) {
                const long base = (long)bb * TF + (t2 - TH);
                if (s < NN) {
                    dinv_s[s] = dinvG[base * NN + s];
                    G_s[s]    = GG[base * NN + s];
                }
                for (int i2 = s; i2 < NN * 3; i2 += 256)
                    maskL[i2] = maskG[base * (NN * 3) + i2];
                const float4* fb4 = (const float4*)(feature + ((long)bb * 48 + t2) * (NN * FF));
                for (int idx = s; idx < NN * 2; idx += 256) {
                    float4 v = fb4[idx];
                    int row = idx >> 1, hf = idx & 1;
                    unsigned short* dst = &Ax[row * STRX + 1 + hf * 4];
                    dst[0] = f2bf(v.x); dst[1] = f2bf(v.y);
                    dst[2] = f2bf(v.z); dst[3] = f2bf(v.w);
                }
            }
        }
        __syncthreads();

        if (t == TH - 1)
            load_phase(WaF, barrF, fcow, fcob);   // fcls rewrite safe: post-barrier
        p ^= 1;
    }
}

extern "C" void kernel_launch(void* const* d_in, const int* in_sizes, int n_in,
                              void* d_out, int out_size, void* d_ws, size_t ws_size,
                              hipStream_t stream) {
    const float* feature = (const float*)d_in[0];
    const float* pm25    = (const float*)d_in[1];
    const float* adj     = (const float*)d_in[2];
    const float* angles  = (const float*)d_in[3];
    const float* W_ih_h  = (const float*)d_in[4];
    const float* W_hh_h  = (const float*)d_in[5];
    const float* b_ih_h  = (const float*)d_in[6];
    const float* b_hh_h  = (const float*)d_in[7];
    const float* fch_w   = (const float*)d_in[8];
    const float* fch_b   = (const float*)d_in[9];
    const float* cw0     = (const float*)d_in[10];
    const float* cw1     = (const float*)d_in[11];
    const float* cbb     = (const float*)d_in[12];
    const float* W_ih    = (const float*)d_in[13];
    const float* W_hh    = (const float*)d_in[14];
    const float* b_ih    = (const float*)d_in[15];
    const float* b_hh    = (const float*)d_in[16];
    const float* fco_w   = (const float*)d_in[17];
    const float* fco_b   = (const float*)d_in[18];
    float* pred = (float*)d_out;

    char* ws = (char*)d_ws;
    size_t off = 0;
    unsigned short* WaH   = (unsigned short*)(ws + off); off += (size_t)NG * KA * 2;       //   163,840
    unsigned short* WaF   = (unsigned short*)(ws + off); off += (size_t)NG * KA * 2;
    float*          barrH = (float*)(ws + off);          off += (size_t)NG * 4;
    float*          barrF = (float*)(ws + off);          off += (size_t)NG * 4;
    float4*         edges = (float4*)(ws + off);         off += (size_t)NN * NN * 16;      //   541,696
    int*            cnt   = (int*)(ws + off);            off += 16;
    unsigned long long* maskG = (unsigned long long*)(ws + off);
    off += (size_t)BB * TF * NN * 3 * 8;                                                   // 27,131,904
    float* dinvG = (float*)(ws + off); off += (size_t)BB * TF * NN * 4;                    //  4,521,984
    float* GG    = (float*)(ws + off); off += (size_t)BB * TF * NN * 4;                    //  4,521,984

    hipMemsetAsync(cnt, 0, 16, stream);
    prep_weights<<<(NG * KA + 255) / 256, 256, 0, stream>>>(
        W_hh_h, W_ih_h, W_hh, W_ih, b_ih_h, b_hh_h, b_ih, b_hh,
        WaH, WaF, barrH, barrF);
    prep_edges<<<(NN * NN + 255) / 256, 256, 0, stream>>>(angles, adj, edges, cnt);
    prep_graph<<<BB * TF, 256, 0, stream>>>(
        feature, edges, cnt, cw0, cw1, cbb, maskG, dinvG, GG);

    fused_dgc<<<BB, NT, 0, stream>>>(
        feature, pm25, WaH, barrH, WaF, barrF,
        fch_w, fch_b, fco_w, fco_b, cw0, cw1,
        maskG, dinvG, GG, pred);
}